// Round 1
// baseline (845.449 us; speedup 1.0000x reference)
//
#include <hip/hip_runtime.h>

#define N_NODES 100000
#define IN_F 256
#define OUT_F 256
#define NROWS N_NODES
#define NBLK ((NROWS + 255) / 256)   // 391 scan blocks
#define MSTRIPS (N_NODES / 32)       // 3125 strips of 32 rows
#define GEMM_BLOCKS ((MSTRIPS + 3) / 4)  // 782

typedef float f32x4 __attribute__((ext_vector_type(4)));
typedef __bf16 bf16x8 __attribute__((ext_vector_type(8)));

// ---------- W transpose + bf16 convert: Wt[n][k] ----------
__global__ __launch_bounds__(256) void prep_w_kernel(const float* __restrict__ W,
                                                     __bf16* __restrict__ Wt) {
    int n = blockIdx.x;
    int k = threadIdx.x;
    Wt[n * IN_F + k] = (__bf16)W[k * OUT_F + n];
}

// ---------- fused: h = x @ W + bias (blocks < GEMM_BLOCKS) | deg histogram ----------
__global__ __launch_bounds__(256, 2) void gemm_count_kernel(const float* __restrict__ x,
                                                            const __bf16* __restrict__ Wt,
                                                            const float* __restrict__ bias,
                                                            __bf16* __restrict__ h,
                                                            const int* __restrict__ rows,
                                                            int* __restrict__ deg, int nE) {
    if (blockIdx.x >= GEMM_BLOCKS) {
        // ---- degree histogram, 4 edges/thread ----
        int i = (blockIdx.x - GEMM_BLOCKS) * 1024 + threadIdx.x * 4;
        if (i + 3 < nE) {
            int4 rr = *(const int4*)(rows + i);
            atomicAdd(&deg[rr.x], 1);
            atomicAdd(&deg[rr.y], 1);
            atomicAdd(&deg[rr.z], 1);
            atomicAdd(&deg[rr.w], 1);
        } else {
            for (int e = i; e < nE; ++e) atomicAdd(&deg[rows[e]], 1);
        }
        return;
    }

    int wave = (blockIdx.x << 2) | (threadIdx.x >> 6);
    if (wave >= MSTRIPS) return;
    int lane = threadIdx.x & 63;
    int r16 = lane & 15;
    int quad = lane >> 4;

    const float*  xp0 = x + (size_t)(wave * 32 + r16) * IN_F + quad * 8;
    const float*  xp1 = xp0 + (size_t)16 * IN_F;
    const __bf16* wp  = Wt + (size_t)r16 * IN_F + quad * 8;

    f32x4 acc[2][16];
#pragma unroll
    for (int m = 0; m < 2; ++m)
#pragma unroll
        for (int i = 0; i < 16; ++i) acc[m][i] = (f32x4){0.f, 0.f, 0.f, 0.f};

#pragma unroll
    for (int k0 = 0; k0 < IN_F; k0 += 32) {
        f32x4 x00 = *(const f32x4*)(xp0 + k0);
        f32x4 x01 = *(const f32x4*)(xp0 + k0 + 4);
        f32x4 x10 = *(const f32x4*)(xp1 + k0);
        f32x4 x11 = *(const f32x4*)(xp1 + k0 + 4);
        bf16x8 a0, a1;
#pragma unroll
        for (int j = 0; j < 4; ++j) {
            a0[j] = (__bf16)x00[j]; a0[j + 4] = (__bf16)x01[j];
            a1[j] = (__bf16)x10[j]; a1[j + 4] = (__bf16)x11[j];
        }
#pragma unroll
        for (int nt = 0; nt < 16; ++nt) {
            bf16x8 b = *(const bf16x8*)(wp + (size_t)nt * 16 * IN_F + k0);
            acc[0][nt] = __builtin_amdgcn_mfma_f32_16x16x32_bf16(a0, b, acc[0][nt], 0, 0, 0);
            acc[1][nt] = __builtin_amdgcn_mfma_f32_16x16x32_bf16(a1, b, acc[1][nt], 0, 0, 0);
        }
    }

#pragma unroll
    for (int m = 0; m < 2; ++m)
#pragma unroll
        for (int nt = 0; nt < 16; ++nt) {
            float bv = bias[nt * 16 + r16];
            __bf16* hp = h + (size_t)(wave * 32 + m * 16 + quad * 4) * OUT_F + nt * 16 + r16;
#pragma unroll
            for (int r = 0; r < 4; ++r)
                hp[(size_t)r * OUT_F] = (__bf16)(acc[m][nt][r] + bv);
        }
}

// ---------- CSR scan ----------
__global__ __launch_bounds__(256) void partial_kernel(const int* __restrict__ deg,
                                                      int* __restrict__ partial) {
    __shared__ int s[256];
    int i = blockIdx.x * 256 + threadIdx.x;
    s[threadIdx.x] = (i < NROWS) ? deg[i] : 0;
    __syncthreads();
    for (int d = 128; d > 0; d >>= 1) {
        if (threadIdx.x < d) s[threadIdx.x] += s[threadIdx.x + d];
        __syncthreads();
    }
    if (threadIdx.x == 0) partial[blockIdx.x] = s[0];
}

__global__ __launch_bounds__(512) void scan_partial_kernel(const int* __restrict__ partial,
                                                           int* __restrict__ blockoff,
                                                           int* __restrict__ row_start, int nE) {
    __shared__ int s[512];
    int t = threadIdx.x;
    int v = (t < NBLK) ? partial[t] : 0;
    s[t] = v;
    __syncthreads();
    for (int d = 1; d < 512; d <<= 1) {
        int u = (t >= d) ? s[t - d] : 0;
        __syncthreads();
        s[t] += u;
        __syncthreads();
    }
    if (t < NBLK) blockoff[t] = s[t] - v;
    if (t == 0) row_start[NROWS] = nE;
}

// writes row_start (exclusive) AND rewrites deg[i] to the inclusive scan
// (row end cursor) so scatter needs no extra row_start read.
__global__ __launch_bounds__(256) void scan_rows_kernel(int* __restrict__ deg,
                                                        const int* __restrict__ blockoff,
                                                        int* __restrict__ row_start) {
    __shared__ int s[256];
    int t = threadIdx.x;
    int i = blockIdx.x * 256 + t;
    int v = (i < NROWS) ? deg[i] : 0;
    s[t] = v;
    __syncthreads();
    for (int d = 1; d < 256; d <<= 1) {
        int u = (t >= d) ? s[t - d] : 0;
        __syncthreads();
        s[t] += u;
        __syncthreads();
    }
    if (i < NROWS) {
        int inc = blockoff[blockIdx.x] + s[t];
        row_start[i] = inc - v;
        deg[i] = inc;            // end cursor consumed by scatter's atomicSub
    }
}

// pos = atomicSub(&cursor[r],1) - 1; cursor holds row END index.
// 4 edges/thread, packed 8B nontemporal stores.
__global__ __launch_bounds__(256) void scatter_kernel(const int* __restrict__ rows,
                                                      const int* __restrict__ cols,
                                                      const float* __restrict__ vals,
                                                      int* __restrict__ cursor,
                                                      long long* __restrict__ sorted, int nE) {
    int i = (blockIdx.x * 256 + threadIdx.x) * 4;
    if (i + 3 < nE) {
        int4 rr = *(const int4*)(rows + i);
        int4 cc = *(const int4*)(cols + i);
        float4 vv = *(const float4*)(vals + i);
        int p0 = atomicSub(&cursor[rr.x], 1) - 1;
        int p1 = atomicSub(&cursor[rr.y], 1) - 1;
        int p2 = atomicSub(&cursor[rr.z], 1) - 1;
        int p3 = atomicSub(&cursor[rr.w], 1) - 1;
        long long e0 = (long long)(((unsigned long long)(unsigned)__float_as_int(vv.x) << 32) | (unsigned)cc.x);
        long long e1 = (long long)(((unsigned long long)(unsigned)__float_as_int(vv.y) << 32) | (unsigned)cc.y);
        long long e2 = (long long)(((unsigned long long)(unsigned)__float_as_int(vv.z) << 32) | (unsigned)cc.z);
        long long e3 = (long long)(((unsigned long long)(unsigned)__float_as_int(vv.w) << 32) | (unsigned)cc.w);
        __builtin_nontemporal_store(e0, sorted + p0);
        __builtin_nontemporal_store(e1, sorted + p1);
        __builtin_nontemporal_store(e2, sorted + p2);
        __builtin_nontemporal_store(e3, sorted + p3);
    } else {
        for (int e = i; e < nE; ++e) {
            int r = rows[e];
            int pos = atomicSub(&cursor[r], 1) - 1;
            long long pk = (long long)(((unsigned long long)(unsigned)__float_as_int(vals[e]) << 32) | (unsigned)cols[e]);
            __builtin_nontemporal_store(pk, sorted + pos);
        }
    }
}

// ---------- SpMM: 2 rows/wave (32 lanes/row) ----------
// Software-pipelined: sorted entries prefetched one 8-batch ahead (q) so
// gathers never wait on the packed-edge load; launch_bounds(256,4) grants
// ~128 VGPR so all 8 gathers + 8 prefetches stay in flight.
// Tail is one masked 8-wide batch (clamped dup addresses = cache hits).
__global__ __launch_bounds__(256, 4) void spmm_csr_kernel(const int* __restrict__ row_start,
                                                          const long long* __restrict__ sorted,
                                                          const __bf16* __restrict__ h,
                                                          float* __restrict__ out) {
    int half = threadIdx.x >> 5;           // 0..7 half-waves per block
    int sub  = threadIdx.x & 31;
    int r = blockIdx.x * 8 + half;
    int e0 = row_start[r];
    int e1 = row_start[r + 1];

    f32x4 a0 = {0.f,0.f,0.f,0.f}, a1 = {0.f,0.f,0.f,0.f};   // even edges
    f32x4 b0 = {0.f,0.f,0.f,0.f}, b1 = {0.f,0.f,0.f,0.f};   // odd edges

    int e = e0;
    if (e + 8 <= e1) {
        long long p[8];
#pragma unroll
        for (int j = 0; j < 8; ++j) p[j] = __builtin_nontemporal_load(sorted + e + j);
        e += 8;
        for (; e + 8 <= e1; e += 8) {
            // issue all 8 gathers (addresses from p, loaded last iteration)
            bf16x8 g[8];
#pragma unroll
            for (int j = 0; j < 8; ++j)
                g[j] = ((const bf16x8*)(h + (size_t)(int)p[j] * OUT_F))[sub];
            // prefetch next batch of packed edges (independent of gathers)
            long long q[8];
#pragma unroll
            for (int j = 0; j < 8; ++j) q[j] = __builtin_nontemporal_load(sorted + e + j);
            // consume gathers
#pragma unroll
            for (int j = 0; j < 8; ++j) {
                float v = __int_as_float((int)(p[j] >> 32));
#pragma unroll
                for (int k = 0; k < 4; ++k) {
                    if (j & 1) { b0[k] += v * (float)g[j][k]; b1[k] += v * (float)g[j][k + 4]; }
                    else       { a0[k] += v * (float)g[j][k]; a1[k] += v * (float)g[j][k + 4]; }
                }
            }
#pragma unroll
            for (int j = 0; j < 8; ++j) p[j] = q[j];
        }
        // drain the last full batch
        {
            bf16x8 g[8];
#pragma unroll
            for (int j = 0; j < 8; ++j)
                g[j] = ((const bf16x8*)(h + (size_t)(int)p[j] * OUT_F))[sub];
#pragma unroll
            for (int j = 0; j < 8; ++j) {
                float v = __int_as_float((int)(p[j] >> 32));
#pragma unroll
                for (int k = 0; k < 4; ++k) {
                    if (j & 1) { b0[k] += v * (float)g[j][k]; b1[k] += v * (float)g[j][k + 4]; }
                    else       { a0[k] += v * (float)g[j][k]; a1[k] += v * (float)g[j][k + 4]; }
                }
            }
        }
    }
    if (e < e1) {
        // masked 8-wide tail: indices clamped to e1-1 (dup loads hit cache), v=0 when OOB
        int rem = e1 - e;                   // 1..7
        long long t[8];
#pragma unroll
        for (int j = 0; j < 8; ++j) {
            int idx = e + j;
            if (idx > e1 - 1) idx = e1 - 1;
            t[j] = __builtin_nontemporal_load(sorted + idx);
        }
        bf16x8 g[8];
#pragma unroll
        for (int j = 0; j < 8; ++j)
            g[j] = ((const bf16x8*)(h + (size_t)(int)t[j] * OUT_F))[sub];
#pragma unroll
        for (int j = 0; j < 8; ++j) {
            float v = (j < rem) ? __int_as_float((int)(t[j] >> 32)) : 0.f;
#pragma unroll
            for (int k = 0; k < 4; ++k) {
                if (j & 1) { b0[k] += v * (float)g[j][k]; b1[k] += v * (float)g[j][k + 4]; }
                else       { a0[k] += v * (float)g[j][k]; a1[k] += v * (float)g[j][k + 4]; }
            }
        }
    }
#pragma unroll
    for (int k = 0; k < 4; ++k) { a0[k] += b0[k]; a1[k] += b1[k]; }
    float* op = out + (size_t)r * OUT_F + sub * 8;
    ((f32x4*)op)[0] = a0;
    ((f32x4*)op)[1] = a1;
}

extern "C" void kernel_launch(void* const* d_in, const int* in_sizes, int n_in,
                              void* d_out, int out_size, void* d_ws, size_t ws_size,
                              hipStream_t stream) {
    const float* x         = (const float*)d_in[0];
    const int*   edge_rows = (const int*)d_in[1];
    const int*   edge_cols = (const int*)d_in[2];
    const float* adj_vals  = (const float*)d_in[3];
    const float* weight    = (const float*)d_in[4];
    const float* bias      = (const float*)d_in[5];
    float* out = (float*)d_out;
    int nE = in_sizes[1];

    // ---- workspace layout (~78 MB total) ----
    char* w = (char*)d_ws;
    __bf16* h  = (__bf16*)w;  w += (size_t)N_NODES * OUT_F * sizeof(__bf16);   // 51.2 MB
    __bf16* Wt = (__bf16*)w;  w += (size_t)IN_F * OUT_F * sizeof(__bf16);      // 128 KB
    int* deg       = (int*)w; w += (size_t)NROWS * 4;
    int* row_start = (int*)w; w += (size_t)(NROWS + 1) * 4 + 12;
    int* partial   = (int*)w; w += (size_t)NBLK * 4;
    int* blockoff  = (int*)w; w += (size_t)NBLK * 4 + 8;
    long long* sorted = (long long*)w;                                         // 25.6 MB

    hipMemsetAsync(deg, 0, (size_t)NROWS * sizeof(int), stream);
    prep_w_kernel<<<OUT_F, IN_F, 0, stream>>>(weight, Wt);

    int countBlocks = (nE + 1023) / 1024;
    gemm_count_kernel<<<GEMM_BLOCKS + countBlocks, 256, 0, stream>>>(x, Wt, bias, h,
                                                                     edge_rows, deg, nE);

    partial_kernel<<<NBLK, 256, 0, stream>>>(deg, partial);
    scan_partial_kernel<<<1, 512, 0, stream>>>(partial, blockoff, row_start, nE);
    scan_rows_kernel<<<NBLK, 256, 0, stream>>>(deg, blockoff, row_start);
    int scatterBlocks = (nE + 1023) / 1024;
    scatter_kernel<<<scatterBlocks, 256, 0, stream>>>(edge_rows, edge_cols, adj_vals,
                                                      deg, sorted, nE);
    spmm_csr_kernel<<<NROWS / 8, 256, 0, stream>>>(row_start, sorted, h, out);
}

// Round 2
// 816.150 us; speedup vs baseline: 1.0359x; 1.0359x over previous
//
#include <hip/hip_runtime.h>

#define N_NODES 100000
#define IN_F 256
#define OUT_F 256
#define NROWS N_NODES
#define NBLK ((NROWS + 255) / 256)   // 391 scan blocks
#define MSTRIPS (N_NODES / 32)       // 3125 strips of 32 rows
#define GEMM_BLOCKS ((MSTRIPS + 3) / 4)  // 782

typedef float f32x4 __attribute__((ext_vector_type(4)));
typedef __bf16 bf16x8 __attribute__((ext_vector_type(8)));

// ---------- W transpose + bf16 convert: Wt[n][k] ----------
__global__ __launch_bounds__(256) void prep_w_kernel(const float* __restrict__ W,
                                                     __bf16* __restrict__ Wt) {
    int n = blockIdx.x;
    int k = threadIdx.x;
    Wt[n * IN_F + k] = (__bf16)W[k * OUT_F + n];
}

// ---------- fused: h = x @ W + bias (blocks < GEMM_BLOCKS) | deg histogram ----------
__global__ __launch_bounds__(256, 2) void gemm_count_kernel(const float* __restrict__ x,
                                                            const __bf16* __restrict__ Wt,
                                                            const float* __restrict__ bias,
                                                            __bf16* __restrict__ h,
                                                            const int* __restrict__ rows,
                                                            int* __restrict__ deg, int nE) {
    if (blockIdx.x >= GEMM_BLOCKS) {
        // ---- degree histogram, 4 edges/thread ----
        int i = (blockIdx.x - GEMM_BLOCKS) * 1024 + threadIdx.x * 4;
        if (i + 3 < nE) {
            int4 rr = *(const int4*)(rows + i);
            atomicAdd(&deg[rr.x], 1);
            atomicAdd(&deg[rr.y], 1);
            atomicAdd(&deg[rr.z], 1);
            atomicAdd(&deg[rr.w], 1);
        } else {
            for (int e = i; e < nE; ++e) atomicAdd(&deg[rows[e]], 1);
        }
        return;
    }

    int wave = (blockIdx.x << 2) | (threadIdx.x >> 6);
    if (wave >= MSTRIPS) return;
    int lane = threadIdx.x & 63;
    int r16 = lane & 15;
    int quad = lane >> 4;

    const float*  xp0 = x + (size_t)(wave * 32 + r16) * IN_F + quad * 8;
    const float*  xp1 = xp0 + (size_t)16 * IN_F;
    const __bf16* wp  = Wt + (size_t)r16 * IN_F + quad * 8;

    f32x4 acc[2][16];
#pragma unroll
    for (int m = 0; m < 2; ++m)
#pragma unroll
        for (int i = 0; i < 16; ++i) acc[m][i] = (f32x4){0.f, 0.f, 0.f, 0.f};

#pragma unroll
    for (int k0 = 0; k0 < IN_F; k0 += 32) {
        f32x4 x00 = *(const f32x4*)(xp0 + k0);
        f32x4 x01 = *(const f32x4*)(xp0 + k0 + 4);
        f32x4 x10 = *(const f32x4*)(xp1 + k0);
        f32x4 x11 = *(const f32x4*)(xp1 + k0 + 4);
        bf16x8 a0, a1;
#pragma unroll
        for (int j = 0; j < 4; ++j) {
            a0[j] = (__bf16)x00[j]; a0[j + 4] = (__bf16)x01[j];
            a1[j] = (__bf16)x10[j]; a1[j + 4] = (__bf16)x11[j];
        }
#pragma unroll
        for (int nt = 0; nt < 16; ++nt) {
            bf16x8 b = *(const bf16x8*)(wp + (size_t)nt * 16 * IN_F + k0);
            acc[0][nt] = __builtin_amdgcn_mfma_f32_16x16x32_bf16(a0, b, acc[0][nt], 0, 0, 0);
            acc[1][nt] = __builtin_amdgcn_mfma_f32_16x16x32_bf16(a1, b, acc[1][nt], 0, 0, 0);
        }
    }

#pragma unroll
    for (int m = 0; m < 2; ++m)
#pragma unroll
        for (int nt = 0; nt < 16; ++nt) {
            float bv = bias[nt * 16 + r16];
            __bf16* hp = h + (size_t)(wave * 32 + m * 16 + quad * 4) * OUT_F + nt * 16 + r16;
#pragma unroll
            for (int r = 0; r < 4; ++r)
                hp[(size_t)r * OUT_F] = (__bf16)(acc[m][nt][r] + bv);
        }
}

// ---------- CSR scan ----------
__global__ __launch_bounds__(256) void partial_kernel(const int* __restrict__ deg,
                                                      int* __restrict__ partial) {
    __shared__ int s[256];
    int i = blockIdx.x * 256 + threadIdx.x;
    s[threadIdx.x] = (i < NROWS) ? deg[i] : 0;
    __syncthreads();
    for (int d = 128; d > 0; d >>= 1) {
        if (threadIdx.x < d) s[threadIdx.x] += s[threadIdx.x + d];
        __syncthreads();
    }
    if (threadIdx.x == 0) partial[blockIdx.x] = s[0];
}

__global__ __launch_bounds__(512) void scan_partial_kernel(const int* __restrict__ partial,
                                                           int* __restrict__ blockoff,
                                                           int* __restrict__ row_start, int nE) {
    __shared__ int s[512];
    int t = threadIdx.x;
    int v = (t < NBLK) ? partial[t] : 0;
    s[t] = v;
    __syncthreads();
    for (int d = 1; d < 512; d <<= 1) {
        int u = (t >= d) ? s[t - d] : 0;
        __syncthreads();
        s[t] += u;
        __syncthreads();
    }
    if (t < NBLK) blockoff[t] = s[t] - v;
    if (t == 0) row_start[NROWS] = nE;
}

// writes row_start (exclusive) AND rewrites deg[i] to the inclusive scan
// (row end cursor) so scatter needs no extra row_start read.
__global__ __launch_bounds__(256) void scan_rows_kernel(int* __restrict__ deg,
                                                        const int* __restrict__ blockoff,
                                                        int* __restrict__ row_start) {
    __shared__ int s[256];
    int t = threadIdx.x;
    int i = blockIdx.x * 256 + t;
    int v = (i < NROWS) ? deg[i] : 0;
    s[t] = v;
    __syncthreads();
    for (int d = 1; d < 256; d <<= 1) {
        int u = (t >= d) ? s[t - d] : 0;
        __syncthreads();
        s[t] += u;
        __syncthreads();
    }
    if (i < NROWS) {
        int inc = blockoff[blockIdx.x] + s[t];
        row_start[i] = inc - v;
        deg[i] = inc;            // end cursor consumed by scatter's atomicSub
    }
}

// pos = atomicSub(&cursor[r],1) - 1; cursor holds row END index.
// 4 edges/thread. PLAIN stores (not nontemporal): the 25.6 MB sorted
// buffer fits aggregate L2, which coalesces the 8x8B entries per line
// into full-line writebacks. NT stores here caused 8x write amplification
// (200 MB HBM writes, row-miss bound, 275 us) in round 1.
__global__ __launch_bounds__(256) void scatter_kernel(const int* __restrict__ rows,
                                                      const int* __restrict__ cols,
                                                      const float* __restrict__ vals,
                                                      int* __restrict__ cursor,
                                                      long long* __restrict__ sorted, int nE) {
    int i = (blockIdx.x * 256 + threadIdx.x) * 4;
    if (i + 3 < nE) {
        int4 rr = *(const int4*)(rows + i);
        int4 cc = *(const int4*)(cols + i);
        float4 vv = *(const float4*)(vals + i);
        int p0 = atomicSub(&cursor[rr.x], 1) - 1;
        int p1 = atomicSub(&cursor[rr.y], 1) - 1;
        int p2 = atomicSub(&cursor[rr.z], 1) - 1;
        int p3 = atomicSub(&cursor[rr.w], 1) - 1;
        long long e0 = (long long)(((unsigned long long)(unsigned)__float_as_int(vv.x) << 32) | (unsigned)cc.x);
        long long e1 = (long long)(((unsigned long long)(unsigned)__float_as_int(vv.y) << 32) | (unsigned)cc.y);
        long long e2 = (long long)(((unsigned long long)(unsigned)__float_as_int(vv.z) << 32) | (unsigned)cc.z);
        long long e3 = (long long)(((unsigned long long)(unsigned)__float_as_int(vv.w) << 32) | (unsigned)cc.w);
        sorted[p0] = e0;
        sorted[p1] = e1;
        sorted[p2] = e2;
        sorted[p3] = e3;
    } else {
        for (int e = i; e < nE; ++e) {
            int r = rows[e];
            int pos = atomicSub(&cursor[r], 1) - 1;
            long long pk = (long long)(((unsigned long long)(unsigned)__float_as_int(vals[e]) << 32) | (unsigned)cols[e]);
            sorted[pos] = pk;
        }
    }
}

// ---------- SpMM: 2 rows/wave (32 lanes/row) ----------
// Software-pipelined: sorted entries prefetched one 8-batch ahead (q) so
// gathers never wait on the packed-edge load; launch_bounds(256,4) grants
// ~128 VGPR so all 8 gathers + 8 prefetches stay in flight.
// Tail is one masked 8-wide batch (clamped dup addresses = cache hits).
__global__ __launch_bounds__(256, 4) void spmm_csr_kernel(const int* __restrict__ row_start,
                                                          const long long* __restrict__ sorted,
                                                          const __bf16* __restrict__ h,
                                                          float* __restrict__ out) {
    int half = threadIdx.x >> 5;           // 0..7 half-waves per block
    int sub  = threadIdx.x & 31;
    int r = blockIdx.x * 8 + half;
    int e0 = row_start[r];
    int e1 = row_start[r + 1];

    f32x4 a0 = {0.f,0.f,0.f,0.f}, a1 = {0.f,0.f,0.f,0.f};   // even edges
    f32x4 b0 = {0.f,0.f,0.f,0.f}, b1 = {0.f,0.f,0.f,0.f};   // odd edges

    int e = e0;
    if (e + 8 <= e1) {
        long long p[8];
#pragma unroll
        for (int j = 0; j < 8; ++j) p[j] = __builtin_nontemporal_load(sorted + e + j);
        e += 8;
        for (; e + 8 <= e1; e += 8) {
            // issue all 8 gathers (addresses from p, loaded last iteration)
            bf16x8 g[8];
#pragma unroll
            for (int j = 0; j < 8; ++j)
                g[j] = ((const bf16x8*)(h + (size_t)(int)p[j] * OUT_F))[sub];
            // prefetch next batch of packed edges (independent of gathers)
            long long q[8];
#pragma unroll
            for (int j = 0; j < 8; ++j) q[j] = __builtin_nontemporal_load(sorted + e + j);
            // consume gathers
#pragma unroll
            for (int j = 0; j < 8; ++j) {
                float v = __int_as_float((int)(p[j] >> 32));
#pragma unroll
                for (int k = 0; k < 4; ++k) {
                    if (j & 1) { b0[k] += v * (float)g[j][k]; b1[k] += v * (float)g[j][k + 4]; }
                    else       { a0[k] += v * (float)g[j][k]; a1[k] += v * (float)g[j][k + 4]; }
                }
            }
#pragma unroll
            for (int j = 0; j < 8; ++j) p[j] = q[j];
        }
        // drain the last full batch
        {
            bf16x8 g[8];
#pragma unroll
            for (int j = 0; j < 8; ++j)
                g[j] = ((const bf16x8*)(h + (size_t)(int)p[j] * OUT_F))[sub];
#pragma unroll
            for (int j = 0; j < 8; ++j) {
                float v = __int_as_float((int)(p[j] >> 32));
#pragma unroll
                for (int k = 0; k < 4; ++k) {
                    if (j & 1) { b0[k] += v * (float)g[j][k]; b1[k] += v * (float)g[j][k + 4]; }
                    else       { a0[k] += v * (float)g[j][k]; a1[k] += v * (float)g[j][k + 4]; }
                }
            }
        }
    }
    if (e < e1) {
        // masked 8-wide tail: indices clamped to e1-1 (dup loads hit cache), v=0 when OOB
        int rem = e1 - e;                   // 1..7
        long long t[8];
#pragma unroll
        for (int j = 0; j < 8; ++j) {
            int idx = e + j;
            if (idx > e1 - 1) idx = e1 - 1;
            t[j] = __builtin_nontemporal_load(sorted + idx);
        }
        bf16x8 g[8];
#pragma unroll
        for (int j = 0; j < 8; ++j)
            g[j] = ((const bf16x8*)(h + (size_t)(int)t[j] * OUT_F))[sub];
#pragma unroll
        for (int j = 0; j < 8; ++j) {
            float v = (j < rem) ? __int_as_float((int)(t[j] >> 32)) : 0.f;
#pragma unroll
            for (int k = 0; k < 4; ++k) {
                if (j & 1) { b0[k] += v * (float)g[j][k]; b1[k] += v * (float)g[j][k + 4]; }
                else       { a0[k] += v * (float)g[j][k]; a1[k] += v * (float)g[j][k + 4]; }
            }
        }
    }
#pragma unroll
    for (int k = 0; k < 4; ++k) { a0[k] += b0[k]; a1[k] += b1[k]; }
    float* op = out + (size_t)r * OUT_F + sub * 8;
    ((f32x4*)op)[0] = a0;
    ((f32x4*)op)[1] = a1;
}

extern "C" void kernel_launch(void* const* d_in, const int* in_sizes, int n_in,
                              void* d_out, int out_size, void* d_ws, size_t ws_size,
                              hipStream_t stream) {
    const float* x         = (const float*)d_in[0];
    const int*   edge_rows = (const int*)d_in[1];
    const int*   edge_cols = (const int*)d_in[2];
    const float* adj_vals  = (const float*)d_in[3];
    const float* weight    = (const float*)d_in[4];
    const float* bias      = (const float*)d_in[5];
    float* out = (float*)d_out;
    int nE = in_sizes[1];

    // ---- workspace layout (~78 MB total) ----
    char* w = (char*)d_ws;
    __bf16* h  = (__bf16*)w;  w += (size_t)N_NODES * OUT_F * sizeof(__bf16);   // 51.2 MB
    __bf16* Wt = (__bf16*)w;  w += (size_t)IN_F * OUT_F * sizeof(__bf16);      // 128 KB
    int* deg       = (int*)w; w += (size_t)NROWS * 4;
    int* row_start = (int*)w; w += (size_t)(NROWS + 1) * 4 + 12;
    int* partial   = (int*)w; w += (size_t)NBLK * 4;
    int* blockoff  = (int*)w; w += (size_t)NBLK * 4 + 8;
    long long* sorted = (long long*)w;                                         // 25.6 MB

    hipMemsetAsync(deg, 0, (size_t)NROWS * sizeof(int), stream);
    prep_w_kernel<<<OUT_F, IN_F, 0, stream>>>(weight, Wt);

    int countBlocks = (nE + 1023) / 1024;
    gemm_count_kernel<<<GEMM_BLOCKS + countBlocks, 256, 0, stream>>>(x, Wt, bias, h,
                                                                     edge_rows, deg, nE);

    partial_kernel<<<NBLK, 256, 0, stream>>>(deg, partial);
    scan_partial_kernel<<<1, 512, 0, stream>>>(partial, blockoff, row_start, nE);
    scan_rows_kernel<<<NBLK, 256, 0, stream>>>(deg, blockoff, row_start);
    int scatterBlocks = (nE + 1023) / 1024;
    scatter_kernel<<<scatterBlocks, 256, 0, stream>>>(edge_rows, edge_cols, adj_vals,
                                                      deg, sorted, nE);
    spmm_csr_kernel<<<NROWS / 8, 256, 0, stream>>>(row_start, sorted, h, out);
}

// Round 3
// 696.658 us; speedup vs baseline: 1.2136x; 1.1715x over previous
//
#include <hip/hip_runtime.h>

#define N_NODES 100000
#define IN_F 256
#define OUT_F 256
#define NROWS N_NODES
#define NBLK ((NROWS + 255) / 256)   // 391 scan blocks
#define MSTRIPS (N_NODES / 32)       // 3125 strips of 32 rows
#define GEMM_BLOCKS ((MSTRIPS + 3) / 4)  // 782

// ---- bucketed counting sort params ----
#define RPB 512                       // rows per bucket (shift 9)
#define NBUCKET ((NROWS + RPB - 1) / RPB)   // 196
#define E_PER_BLK 4096                // edges per bin block (16/thread)

typedef float f32x4 __attribute__((ext_vector_type(4)));
typedef __bf16 bf16x8 __attribute__((ext_vector_type(8)));

// ---------- W transpose + bf16 convert: Wt[n][k] ----------
__global__ __launch_bounds__(256) void prep_w_kernel(const float* __restrict__ W,
                                                     __bf16* __restrict__ Wt) {
    int n = blockIdx.x;
    int k = threadIdx.x;
    Wt[n * IN_F + k] = (__bf16)W[k * OUT_F + n];
}

// ---------- fused: h = x @ W + bias (blocks < GEMM_BLOCKS) | deg histogram ----------
__global__ __launch_bounds__(256, 2) void gemm_count_kernel(const float* __restrict__ x,
                                                            const __bf16* __restrict__ Wt,
                                                            const float* __restrict__ bias,
                                                            __bf16* __restrict__ h,
                                                            const int* __restrict__ rows,
                                                            int* __restrict__ deg, int nE) {
    if (blockIdx.x >= GEMM_BLOCKS) {
        // ---- degree histogram, 4 edges/thread ----
        int i = (blockIdx.x - GEMM_BLOCKS) * 1024 + threadIdx.x * 4;
        if (i + 3 < nE) {
            int4 rr = *(const int4*)(rows + i);
            atomicAdd(&deg[rr.x], 1);
            atomicAdd(&deg[rr.y], 1);
            atomicAdd(&deg[rr.z], 1);
            atomicAdd(&deg[rr.w], 1);
        } else {
            for (int e = i; e < nE; ++e) atomicAdd(&deg[rows[e]], 1);
        }
        return;
    }

    int wave = (blockIdx.x << 2) | (threadIdx.x >> 6);
    if (wave >= MSTRIPS) return;
    int lane = threadIdx.x & 63;
    int r16 = lane & 15;
    int quad = lane >> 4;

    const float*  xp0 = x + (size_t)(wave * 32 + r16) * IN_F + quad * 8;
    const float*  xp1 = xp0 + (size_t)16 * IN_F;
    const __bf16* wp  = Wt + (size_t)r16 * IN_F + quad * 8;

    f32x4 acc[2][16];
#pragma unroll
    for (int m = 0; m < 2; ++m)
#pragma unroll
        for (int i = 0; i < 16; ++i) acc[m][i] = (f32x4){0.f, 0.f, 0.f, 0.f};

#pragma unroll
    for (int k0 = 0; k0 < IN_F; k0 += 32) {
        f32x4 x00 = *(const f32x4*)(xp0 + k0);
        f32x4 x01 = *(const f32x4*)(xp0 + k0 + 4);
        f32x4 x10 = *(const f32x4*)(xp1 + k0);
        f32x4 x11 = *(const f32x4*)(xp1 + k0 + 4);
        bf16x8 a0, a1;
#pragma unroll
        for (int j = 0; j < 4; ++j) {
            a0[j] = (__bf16)x00[j]; a0[j + 4] = (__bf16)x01[j];
            a1[j] = (__bf16)x10[j]; a1[j + 4] = (__bf16)x11[j];
        }
#pragma unroll
        for (int nt = 0; nt < 16; ++nt) {
            bf16x8 b = *(const bf16x8*)(wp + (size_t)nt * 16 * IN_F + k0);
            acc[0][nt] = __builtin_amdgcn_mfma_f32_16x16x32_bf16(a0, b, acc[0][nt], 0, 0, 0);
            acc[1][nt] = __builtin_amdgcn_mfma_f32_16x16x32_bf16(a1, b, acc[1][nt], 0, 0, 0);
        }
    }

#pragma unroll
    for (int m = 0; m < 2; ++m)
#pragma unroll
        for (int nt = 0; nt < 16; ++nt) {
            float bv = bias[nt * 16 + r16];
            __bf16* hp = h + (size_t)(wave * 32 + m * 16 + quad * 4) * OUT_F + nt * 16 + r16;
#pragma unroll
            for (int r = 0; r < 4; ++r)
                hp[(size_t)r * OUT_F] = (__bf16)(acc[m][nt][r] + bv);
        }
}

// ---------- CSR scan ----------
__global__ __launch_bounds__(256) void partial_kernel(const int* __restrict__ deg,
                                                      int* __restrict__ partial) {
    __shared__ int s[256];
    int i = blockIdx.x * 256 + threadIdx.x;
    s[threadIdx.x] = (i < NROWS) ? deg[i] : 0;
    __syncthreads();
    for (int d = 128; d > 0; d >>= 1) {
        if (threadIdx.x < d) s[threadIdx.x] += s[threadIdx.x + d];
        __syncthreads();
    }
    if (threadIdx.x == 0) partial[blockIdx.x] = s[0];
}

__global__ __launch_bounds__(512) void scan_partial_kernel(const int* __restrict__ partial,
                                                           int* __restrict__ blockoff,
                                                           int* __restrict__ row_start, int nE) {
    __shared__ int s[512];
    int t = threadIdx.x;
    int v = (t < NBLK) ? partial[t] : 0;
    s[t] = v;
    __syncthreads();
    for (int d = 1; d < 512; d <<= 1) {
        int u = (t >= d) ? s[t - d] : 0;
        __syncthreads();
        s[t] += u;
        __syncthreads();
    }
    if (t < NBLK) blockoff[t] = s[t] - v;
    if (t == 0) row_start[NROWS] = nE;
}

__global__ __launch_bounds__(256) void scan_rows_kernel(const int* __restrict__ deg,
                                                        const int* __restrict__ blockoff,
                                                        int* __restrict__ row_start) {
    __shared__ int s[256];
    int t = threadIdx.x;
    int i = blockIdx.x * 256 + t;
    int v = (i < NROWS) ? deg[i] : 0;
    s[t] = v;
    __syncthreads();
    for (int d = 1; d < 256; d <<= 1) {
        int u = (t >= d) ? s[t - d] : 0;
        __syncthreads();
        s[t] += u;
        __syncthreads();
    }
    if (i < NROWS) row_start[i] = blockoff[blockIdx.x] + s[t] - v;
}

// bucket_cur[b] = start of bucket b's CSR segment (buckets are contiguous row
// ranges, so segments are contiguous).
__global__ __launch_bounds__(256) void init_bucket_kernel(const int* __restrict__ row_start,
                                                          int* __restrict__ bucket_cur) {
    int t = threadIdx.x;
    if (t < NBUCKET) {
        int gr = t * RPB;
        bucket_cur[t] = row_start[gr < NROWS ? gr : NROWS];
    }
}

// ---------- pass 1: LDS-binned scatter to bucket segments ----------
// Per block: count 4096 edges into 196 buckets (LDS), reserve one contiguous
// chunk per bucket (1 global atomic each), write edges as dense chunks.
// Chunk writes are same-XCD + temporally clustered -> L2 merges into full
// lines (the single-pass random scatter was 8x write-amplified: 198 MB HBM,
// 260 us, cross-XCD partial lines).
// Entry: (valbits<<32) | (lrow<<17) | col   (col < 2^17, lrow < 2^9)
__global__ __launch_bounds__(256) void bin_kernel(const int* __restrict__ rows,
                                                  const int* __restrict__ cols,
                                                  const float* __restrict__ vals,
                                                  int* __restrict__ bucket_cur,
                                                  unsigned long long* __restrict__ inter,
                                                  int nE) {
    __shared__ int cnt[NBUCKET];
    __shared__ int off[NBUCKET];
    int t = threadIdx.x;
    for (int i = t; i < NBUCKET; i += 256) cnt[i] = 0;
    __syncthreads();
    int base = blockIdx.x * E_PER_BLK;
#pragma unroll
    for (int j = 0; j < 16; ++j) {
        int e = base + j * 256 + t;
        if (e < nE) atomicAdd(&cnt[rows[e] >> 9], 1);
    }
    __syncthreads();
    for (int i = t; i < NBUCKET; i += 256)
        off[i] = cnt[i] ? atomicAdd(&bucket_cur[i], cnt[i]) : 0;
    __syncthreads();
#pragma unroll
    for (int j = 0; j < 16; ++j) {
        int e = base + j * 256 + t;
        if (e < nE) {
            int r = rows[e];
            unsigned c = (unsigned)cols[e];
            unsigned vb = __float_as_uint(vals[e]);
            int b = r >> 9;
            int p = atomicAdd(&off[b], 1);
            inter[p] = ((unsigned long long)vb << 32) |
                       ((unsigned long long)((unsigned)(r & (RPB - 1)) << 17)) | c;
        }
    }
}

// ---------- pass 2: per-bucket counting sort into final CSR order ----------
// One block per bucket: LDS per-row cursors seeded from row_start; streams the
// ~131 KB bucket segment, scatters within the same 131 KB region (one XCD's
// L2 owns it -> full-line writebacks).
__global__ __launch_bounds__(256) void bucket_sort_kernel(const int* __restrict__ row_start,
                                                          const unsigned long long* __restrict__ inter,
                                                          long long* __restrict__ sorted) {
    __shared__ int cur[RPB];
    int t = threadIdx.x;
    int r0 = blockIdx.x * RPB;
    for (int i = t; i < RPB; i += 256) {
        int gr = r0 + i;
        cur[i] = row_start[gr < NROWS ? gr : NROWS];
    }
    __syncthreads();
    int eb = row_start[r0];
    int gend = r0 + RPB; if (gend > NROWS) gend = NROWS;
    int ee = row_start[gend];
    for (int e = eb + t; e < ee; e += 256) {
        unsigned long long pk = inter[e];
        unsigned meta = (unsigned)pk;
        int lr = (meta >> 17) & (RPB - 1);
        unsigned c = meta & 0x1FFFFu;
        int pos = atomicAdd(&cur[lr], 1);
        sorted[pos] = (long long)((pk & 0xFFFFFFFF00000000ull) | c);
    }
}

// ---------- SpMM: 2 rows/wave (32 lanes/row) ----------
// Software-pipelined: sorted entries prefetched one 8-batch ahead (q) so
// gathers never wait on the packed-edge load; launch_bounds(256,4) grants
// ~128 VGPR so all 8 gathers + 8 prefetches stay in flight.
// Tail is one masked 8-wide batch (clamped dup addresses = cache hits).
__global__ __launch_bounds__(256, 4) void spmm_csr_kernel(const int* __restrict__ row_start,
                                                          const long long* __restrict__ sorted,
                                                          const __bf16* __restrict__ h,
                                                          float* __restrict__ out) {
    int half = threadIdx.x >> 5;           // 0..7 half-waves per block
    int sub  = threadIdx.x & 31;
    int r = blockIdx.x * 8 + half;
    int e0 = row_start[r];
    int e1 = row_start[r + 1];

    f32x4 a0 = {0.f,0.f,0.f,0.f}, a1 = {0.f,0.f,0.f,0.f};   // even edges
    f32x4 b0 = {0.f,0.f,0.f,0.f}, b1 = {0.f,0.f,0.f,0.f};   // odd edges

    int e = e0;
    if (e + 8 <= e1) {
        long long p[8];
#pragma unroll
        for (int j = 0; j < 8; ++j) p[j] = __builtin_nontemporal_load(sorted + e + j);
        e += 8;
        for (; e + 8 <= e1; e += 8) {
            // issue all 8 gathers (addresses from p, loaded last iteration)
            bf16x8 g[8];
#pragma unroll
            for (int j = 0; j < 8; ++j)
                g[j] = ((const bf16x8*)(h + (size_t)(int)p[j] * OUT_F))[sub];
            // prefetch next batch of packed edges (independent of gathers)
            long long q[8];
#pragma unroll
            for (int j = 0; j < 8; ++j) q[j] = __builtin_nontemporal_load(sorted + e + j);
            // consume gathers
#pragma unroll
            for (int j = 0; j < 8; ++j) {
                float v = __int_as_float((int)(p[j] >> 32));
#pragma unroll
                for (int k = 0; k < 4; ++k) {
                    if (j & 1) { b0[k] += v * (float)g[j][k]; b1[k] += v * (float)g[j][k + 4]; }
                    else       { a0[k] += v * (float)g[j][k]; a1[k] += v * (float)g[j][k + 4]; }
                }
            }
#pragma unroll
            for (int j = 0; j < 8; ++j) p[j] = q[j];
        }
        // drain the last full batch
        {
            bf16x8 g[8];
#pragma unroll
            for (int j = 0; j < 8; ++j)
                g[j] = ((const bf16x8*)(h + (size_t)(int)p[j] * OUT_F))[sub];
#pragma unroll
            for (int j = 0; j < 8; ++j) {
                float v = __int_as_float((int)(p[j] >> 32));
#pragma unroll
                for (int k = 0; k < 4; ++k) {
                    if (j & 1) { b0[k] += v * (float)g[j][k]; b1[k] += v * (float)g[j][k + 4]; }
                    else       { a0[k] += v * (float)g[j][k]; a1[k] += v * (float)g[j][k + 4]; }
                }
            }
        }
    }
    if (e < e1) {
        // masked 8-wide tail: indices clamped to e1-1 (dup loads hit cache), v=0 when OOB
        int rem = e1 - e;                   // 1..7
        long long t[8];
#pragma unroll
        for (int j = 0; j < 8; ++j) {
            int idx = e + j;
            if (idx > e1 - 1) idx = e1 - 1;
            t[j] = __builtin_nontemporal_load(sorted + idx);
        }
        bf16x8 g[8];
#pragma unroll
        for (int j = 0; j < 8; ++j)
            g[j] = ((const bf16x8*)(h + (size_t)(int)t[j] * OUT_F))[sub];
#pragma unroll
        for (int j = 0; j < 8; ++j) {
            float v = (j < rem) ? __int_as_float((int)(t[j] >> 32)) : 0.f;
#pragma unroll
            for (int k = 0; k < 4; ++k) {
                if (j & 1) { b0[k] += v * (float)g[j][k]; b1[k] += v * (float)g[j][k + 4]; }
                else       { a0[k] += v * (float)g[j][k]; a1[k] += v * (float)g[j][k + 4]; }
            }
        }
    }
#pragma unroll
    for (int k = 0; k < 4; ++k) { a0[k] += b0[k]; a1[k] += b1[k]; }
    float* op = out + (size_t)r * OUT_F + sub * 8;
    ((f32x4*)op)[0] = a0;
    ((f32x4*)op)[1] = a1;
}

extern "C" void kernel_launch(void* const* d_in, const int* in_sizes, int n_in,
                              void* d_out, int out_size, void* d_ws, size_t ws_size,
                              hipStream_t stream) {
    const float* x         = (const float*)d_in[0];
    const int*   edge_rows = (const int*)d_in[1];
    const int*   edge_cols = (const int*)d_in[2];
    const float* adj_vals  = (const float*)d_in[3];
    const float* weight    = (const float*)d_in[4];
    const float* bias      = (const float*)d_in[5];
    float* out = (float*)d_out;
    int nE = in_sizes[1];

    // ---- workspace layout (~78 MB total) ----
    char* w = (char*)d_ws;
    __bf16* h  = (__bf16*)w;  w += (size_t)N_NODES * OUT_F * sizeof(__bf16);   // 51.2 MB
    __bf16* Wt = (__bf16*)w;  w += (size_t)IN_F * OUT_F * sizeof(__bf16);      // 128 KB
    int* deg       = (int*)w; w += (size_t)NROWS * 4;
    int* row_start = (int*)w; w += (size_t)(NROWS + 1) * 4 + 12;
    int* partial   = (int*)w; w += (size_t)NBLK * 4;
    int* blockoff  = (int*)w; w += (size_t)NBLK * 4 + 8;
    int* bucket_cur = (int*)w; w += (size_t)NBUCKET * 4 + 16;
    long long* sorted = (long long*)w;                                         // 25.6 MB

    // intermediate (binned) edges alias d_out: 25.6 MB << 102.4 MB, and spmm
    // fully overwrites out afterwards (stream-ordered).
    unsigned long long* inter = (unsigned long long*)d_out;

    hipMemsetAsync(deg, 0, (size_t)NROWS * sizeof(int), stream);
    prep_w_kernel<<<OUT_F, IN_F, 0, stream>>>(weight, Wt);

    int countBlocks = (nE + 1023) / 1024;
    gemm_count_kernel<<<GEMM_BLOCKS + countBlocks, 256, 0, stream>>>(x, Wt, bias, h,
                                                                     edge_rows, deg, nE);

    partial_kernel<<<NBLK, 256, 0, stream>>>(deg, partial);
    scan_partial_kernel<<<1, 512, 0, stream>>>(partial, blockoff, row_start, nE);
    scan_rows_kernel<<<NBLK, 256, 0, stream>>>(deg, blockoff, row_start);
    init_bucket_kernel<<<1, 256, 0, stream>>>(row_start, bucket_cur);

    int binBlocks = (nE + E_PER_BLK - 1) / E_PER_BLK;
    bin_kernel<<<binBlocks, 256, 0, stream>>>(edge_rows, edge_cols, adj_vals,
                                              bucket_cur, inter, nE);
    bucket_sort_kernel<<<NBUCKET, 256, 0, stream>>>(row_start, inter, sorted);

    spmm_csr_kernel<<<NROWS / 8, 256, 0, stream>>>(row_start, sorted, h, out);
}

// Round 5
// 677.312 us; speedup vs baseline: 1.2482x; 1.0286x over previous
//
#include <hip/hip_runtime.h>

#define N_NODES 100000
#define IN_F 256
#define OUT_F 256
#define NROWS N_NODES
#define NBLK ((NROWS + 255) / 256)   // 391 scan blocks
#define MSTRIPS (N_NODES / 32)       // 3125 strips of 32 rows

// GEMM: 2 waves per strip (32 rows x 128 cols each), 4 waves/block
#define GWAVES (MSTRIPS * 2)              // 6250
#define GEMM_BLOCKS ((GWAVES + 3) / 4)    // 1563

// ---- bucketed counting sort params ----
#define RPB 256                       // rows per bucket (shift 8)
#define NBUCKET ((NROWS + RPB - 1) / RPB)   // 391
#define CAP 16384                     // bucket capacity (2x expected 8192)
#define CAPSH 14
#define E_PER_BLK 4096                // edges per bin block (16/thread)
#define MAX_OV 8192

typedef float f32x4 __attribute__((ext_vector_type(4)));
typedef __bf16 bf16x8 __attribute__((ext_vector_type(8)));

// ---------- W transpose + bf16 convert: Wt[n][k] ----------
__global__ __launch_bounds__(256) void prep_w_kernel(const float* __restrict__ W,
                                                     __bf16* __restrict__ Wt) {
    int n = blockIdx.x;
    int k = threadIdx.x;
    Wt[n * IN_F + k] = (__bf16)W[k * OUT_F + n];
}

// ---------- fused launch: GEMM blocks | bin blocks ----------
// GEMM part: h = x @ W + bias. One wave per 32x128 sub-strip (2 m-tiles x
// 8 n-tiles) -> acc is 64 VGPRs (was 128 with 32x256, register-thrashed).
// BIN part (single pass over edges): per 4096-edge block, LDS-count per
// bucket AND global deg atomics; reserve contiguous chunk per bucket at
// static base b*CAP; write packed entries (val<<32 | lrow<<17 | col).
// Overflow (statistically never: CAP = 2x expected) spills to ov_idx.
__global__ __launch_bounds__(256, 2) void gemm_bin_kernel(const float* __restrict__ x,
                                                          const __bf16* __restrict__ Wt,
                                                          const float* __restrict__ bias,
                                                          __bf16* __restrict__ h,
                                                          const int* __restrict__ rows,
                                                          const int* __restrict__ cols,
                                                          const float* __restrict__ vals,
                                                          int* __restrict__ deg,
                                                          int* __restrict__ bcnt,
                                                          int* __restrict__ ov_cnt,
                                                          int* __restrict__ ov_idx,
                                                          unsigned long long* __restrict__ inter,
                                                          int nE) {
    __shared__ int cnt[NBUCKET];
    __shared__ int off[NBUCKET];

    if (blockIdx.x >= GEMM_BLOCKS) {
        // ================= BIN =================
        int bblk = blockIdx.x - GEMM_BLOCKS;
        int t = threadIdx.x;
        for (int i = t; i < NBUCKET; i += 256) cnt[i] = 0;
        __syncthreads();
        int base = bblk * E_PER_BLK;
        int r_[16];
#pragma unroll
        for (int j = 0; j < 4; ++j) {
            int e = base + (j * 256 + t) * 4;
            if (e + 3 < nE) {
                int4 rr = *(const int4*)(rows + e);
                r_[j * 4 + 0] = rr.x; r_[j * 4 + 1] = rr.y;
                r_[j * 4 + 2] = rr.z; r_[j * 4 + 3] = rr.w;
                atomicAdd(&cnt[rr.x >> 8], 1); atomicAdd(&deg[rr.x], 1);
                atomicAdd(&cnt[rr.y >> 8], 1); atomicAdd(&deg[rr.y], 1);
                atomicAdd(&cnt[rr.z >> 8], 1); atomicAdd(&deg[rr.z], 1);
                atomicAdd(&cnt[rr.w >> 8], 1); atomicAdd(&deg[rr.w], 1);
            } else {
#pragma unroll
                for (int k = 0; k < 4; ++k) {
                    int ee = e + k;
                    if (ee < nE) {
                        int r = rows[ee];
                        r_[j * 4 + k] = r;
                        atomicAdd(&cnt[r >> 8], 1);
                        atomicAdd(&deg[r], 1);
                    } else r_[j * 4 + k] = -1;
                }
            }
        }
        __syncthreads();
        for (int i = t; i < NBUCKET; i += 256) {
            int c = cnt[i];
            off[i] = c ? ((i << CAPSH) + atomicAdd(&bcnt[i], c)) : 0;
        }
        __syncthreads();
#pragma unroll
        for (int j = 0; j < 4; ++j) {
            int e = base + (j * 256 + t) * 4;
            if (e + 3 < nE) {
                int4 cc = *(const int4*)(cols + e);
                float4 vv = *(const float4*)(vals + e);
                int rr[4] = {r_[j*4+0], r_[j*4+1], r_[j*4+2], r_[j*4+3]};
                int cc4[4] = {cc.x, cc.y, cc.z, cc.w};
                float vv4[4] = {vv.x, vv.y, vv.z, vv.w};
#pragma unroll
                for (int k = 0; k < 4; ++k) {
                    int r = rr[k];
                    int b = r >> 8;
                    int p = atomicAdd(&off[b], 1);
                    unsigned long long pk =
                        ((unsigned long long)__float_as_uint(vv4[k]) << 32) |
                        ((unsigned)(r & (RPB - 1)) << 17) | (unsigned)cc4[k];
                    if (p < ((b + 1) << CAPSH)) inter[p] = pk;
                    else {
                        int o = atomicAdd(ov_cnt, 1);
                        if (o < MAX_OV) ov_idx[o] = e + k;
                    }
                }
            } else {
#pragma unroll
                for (int k = 0; k < 4; ++k) {
                    int ee = e + k;
                    int r = r_[j * 4 + k];
                    if (r >= 0) {
                        int b = r >> 8;
                        int p = atomicAdd(&off[b], 1);
                        unsigned long long pk =
                            ((unsigned long long)__float_as_uint(vals[ee]) << 32) |
                            ((unsigned)(r & (RPB - 1)) << 17) | (unsigned)cols[ee];
                        if (p < ((b + 1) << CAPSH)) inter[p] = pk;
                        else {
                            int o = atomicAdd(ov_cnt, 1);
                            if (o < MAX_OV) ov_idx[o] = ee;
                        }
                    }
                }
            }
        }
        return;
    }

    // ================= GEMM =================
    int wave = (blockIdx.x << 2) | (threadIdx.x >> 6);
    if (wave >= GWAVES) return;
    int strip = wave >> 1;          // 32-row strip
    int nh = wave & 1;              // which 128-col half
    int lane = threadIdx.x & 63;
    int r16 = lane & 15;
    int quad = lane >> 4;

    const float*  xp0 = x + (size_t)(strip * 32 + r16) * IN_F + quad * 8;
    const float*  xp1 = xp0 + (size_t)16 * IN_F;
    const __bf16* wp  = Wt + (size_t)(nh * 128 + r16) * IN_F + quad * 8;

    f32x4 acc[2][8];
#pragma unroll
    for (int m = 0; m < 2; ++m)
#pragma unroll
        for (int i = 0; i < 8; ++i) acc[m][i] = (f32x4){0.f, 0.f, 0.f, 0.f};

#pragma unroll
    for (int k0 = 0; k0 < IN_F; k0 += 32) {
        f32x4 x00 = *(const f32x4*)(xp0 + k0);
        f32x4 x01 = *(const f32x4*)(xp0 + k0 + 4);
        f32x4 x10 = *(const f32x4*)(xp1 + k0);
        f32x4 x11 = *(const f32x4*)(xp1 + k0 + 4);
        bf16x8 a0, a1;
#pragma unroll
        for (int j = 0; j < 4; ++j) {
            a0[j] = (__bf16)x00[j]; a0[j + 4] = (__bf16)x01[j];
            a1[j] = (__bf16)x10[j]; a1[j + 4] = (__bf16)x11[j];
        }
#pragma unroll
        for (int nt = 0; nt < 8; ++nt) {
            bf16x8 b = *(const bf16x8*)(wp + (size_t)nt * 16 * IN_F + k0);
            acc[0][nt] = __builtin_amdgcn_mfma_f32_16x16x32_bf16(a0, b, acc[0][nt], 0, 0, 0);
            acc[1][nt] = __builtin_amdgcn_mfma_f32_16x16x32_bf16(a1, b, acc[1][nt], 0, 0, 0);
        }
    }

#pragma unroll
    for (int m = 0; m < 2; ++m)
#pragma unroll
        for (int nt = 0; nt < 8; ++nt) {
            int col = nh * 128 + nt * 16 + r16;
            float bv = bias[col];
            __bf16* hp = h + (size_t)(strip * 32 + m * 16 + quad * 4) * OUT_F + col;
#pragma unroll
            for (int r = 0; r < 4; ++r)
                hp[(size_t)r * OUT_F] = (__bf16)(acc[m][nt][r] + bv);
        }
}

// ---------- CSR scan ----------
__global__ __launch_bounds__(256) void partial_kernel(const int* __restrict__ deg,
                                                      int* __restrict__ partial) {
    __shared__ int s[256];
    int i = blockIdx.x * 256 + threadIdx.x;
    s[threadIdx.x] = (i < NROWS) ? deg[i] : 0;
    __syncthreads();
    for (int d = 128; d > 0; d >>= 1) {
        if (threadIdx.x < d) s[threadIdx.x] += s[threadIdx.x + d];
        __syncthreads();
    }
    if (threadIdx.x == 0) partial[blockIdx.x] = s[0];
}

__global__ __launch_bounds__(512) void scan_partial_kernel(const int* __restrict__ partial,
                                                           int* __restrict__ blockoff,
                                                           int* __restrict__ row_start, int nE) {
    __shared__ int s[512];
    int t = threadIdx.x;
    int v = (t < NBLK) ? partial[t] : 0;
    s[t] = v;
    __syncthreads();
    for (int d = 1; d < 512; d <<= 1) {
        int u = (t >= d) ? s[t - d] : 0;
        __syncthreads();
        s[t] += u;
        __syncthreads();
    }
    if (t < NBLK) blockoff[t] = s[t] - v;
    if (t == 0) row_start[NROWS] = nE;
}

__global__ __launch_bounds__(256) void scan_rows_kernel(const int* __restrict__ deg,
                                                        const int* __restrict__ blockoff,
                                                        int* __restrict__ row_start) {
    __shared__ int s[256];
    int t = threadIdx.x;
    int i = blockIdx.x * 256 + t;
    int v = (i < NROWS) ? deg[i] : 0;
    s[t] = v;
    __syncthreads();
    for (int d = 1; d < 256; d <<= 1) {
        int u = (t >= d) ? s[t - d] : 0;
        __syncthreads();
        s[t] += u;
        __syncthreads();
    }
    if (i < NROWS) row_start[i] = blockoff[blockIdx.x] + s[t] - v;
}

// ---------- per-bucket counting sort into final CSR order ----------
__global__ __launch_bounds__(256) void bucket_sort_kernel(const int* __restrict__ row_start,
                                                          const unsigned long long* __restrict__ inter,
                                                          const int* __restrict__ bcnt,
                                                          const int* __restrict__ ov_cnt,
                                                          const int* __restrict__ ov_idx,
                                                          const int* __restrict__ rows,
                                                          const int* __restrict__ cols,
                                                          const float* __restrict__ vals,
                                                          long long* __restrict__ sorted) {
    __shared__ int cur[RPB];
    int t = threadIdx.x;
    int b = blockIdx.x;
    int r0 = b << 8;
    {
        int gr = r0 + t;
        cur[t] = row_start[gr < NROWS ? gr : NROWS];
    }
    __syncthreads();
    int n = bcnt[b]; if (n > CAP) n = CAP;
    const unsigned long long* src = inter + ((size_t)b << CAPSH);
    int base2 = 0;
    for (; base2 + 1024 <= n; base2 += 1024) {
        unsigned long long pk[4];
#pragma unroll
        for (int j = 0; j < 4; ++j) pk[j] = src[base2 + j * 256 + t];
#pragma unroll
        for (int j = 0; j < 4; ++j) {
            unsigned meta = (unsigned)pk[j];
            int lr = (meta >> 17) & (RPB - 1);
            int pos = atomicAdd(&cur[lr], 1);
            sorted[pos] = (long long)((pk[j] & 0xFFFFFFFF00000000ull) | (meta & 0x1FFFFu));
        }
    }
    for (int e = base2 + t; e < n; e += 256) {
        unsigned long long pk = src[e];
        unsigned meta = (unsigned)pk;
        int lr = (meta >> 17) & (RPB - 1);
        int pos = atomicAdd(&cur[lr], 1);
        sorted[pos] = (long long)((pk & 0xFFFFFFFF00000000ull) | (meta & 0x1FFFFu));
    }
    // overflow tail (normally ov=0: one scalar load, no loop)
    int m = *ov_cnt; if (m > MAX_OV) m = MAX_OV;
    for (int i = t; i < m; i += 256) {
        int e = ov_idx[i];
        int r = rows[e];
        if ((r >> 8) == b) {
            int pos = atomicAdd(&cur[r & (RPB - 1)], 1);
            sorted[pos] = (long long)(((unsigned long long)__float_as_uint(vals[e]) << 32) |
                                      (unsigned)cols[e]);
        }
    }
}

// ---------- SpMM: 2 rows/wave (32 lanes/row) ---------- (unchanged control)
__global__ __launch_bounds__(256, 4) void spmm_csr_kernel(const int* __restrict__ row_start,
                                                          const long long* __restrict__ sorted,
                                                          const __bf16* __restrict__ h,
                                                          float* __restrict__ out) {
    int half = threadIdx.x >> 5;           // 0..7 half-waves per block
    int sub  = threadIdx.x & 31;
    int r = blockIdx.x * 8 + half;
    int e0 = row_start[r];
    int e1 = row_start[r + 1];

    f32x4 a0 = {0.f,0.f,0.f,0.f}, a1 = {0.f,0.f,0.f,0.f};   // even edges
    f32x4 b0 = {0.f,0.f,0.f,0.f}, b1 = {0.f,0.f,0.f,0.f};   // odd edges

    int e = e0;
    if (e + 8 <= e1) {
        long long p[8];
#pragma unroll
        for (int j = 0; j < 8; ++j) p[j] = __builtin_nontemporal_load(sorted + e + j);
        e += 8;
        for (; e + 8 <= e1; e += 8) {
            bf16x8 g[8];
#pragma unroll
            for (int j = 0; j < 8; ++j)
                g[j] = ((const bf16x8*)(h + (size_t)(int)p[j] * OUT_F))[sub];
            long long q[8];
#pragma unroll
            for (int j = 0; j < 8; ++j) q[j] = __builtin_nontemporal_load(sorted + e + j);
#pragma unroll
            for (int j = 0; j < 8; ++j) {
                float v = __int_as_float((int)(p[j] >> 32));
#pragma unroll
                for (int k = 0; k < 4; ++k) {
                    if (j & 1) { b0[k] += v * (float)g[j][k]; b1[k] += v * (float)g[j][k + 4]; }
                    else       { a0[k] += v * (float)g[j][k]; a1[k] += v * (float)g[j][k + 4]; }
                }
            }
#pragma unroll
            for (int j = 0; j < 8; ++j) p[j] = q[j];
        }
        {
            bf16x8 g[8];
#pragma unroll
            for (int j = 0; j < 8; ++j)
                g[j] = ((const bf16x8*)(h + (size_t)(int)p[j] * OUT_F))[sub];
#pragma unroll
            for (int j = 0; j < 8; ++j) {
                float v = __int_as_float((int)(p[j] >> 32));
#pragma unroll
                for (int k = 0; k < 4; ++k) {
                    if (j & 1) { b0[k] += v * (float)g[j][k]; b1[k] += v * (float)g[j][k + 4]; }
                    else       { a0[k] += v * (float)g[j][k]; a1[k] += v * (float)g[j][k + 4]; }
                }
            }
        }
    }
    if (e < e1) {
        int rem = e1 - e;                   // 1..7
        long long t[8];
#pragma unroll
        for (int j = 0; j < 8; ++j) {
            int idx = e + j;
            if (idx > e1 - 1) idx = e1 - 1;
            t[j] = __builtin_nontemporal_load(sorted + idx);
        }
        bf16x8 g[8];
#pragma unroll
        for (int j = 0; j < 8; ++j)
            g[j] = ((const bf16x8*)(h + (size_t)(int)t[j] * OUT_F))[sub];
#pragma unroll
        for (int j = 0; j < 8; ++j) {
            float v = (j < rem) ? __int_as_float((int)(t[j] >> 32)) : 0.f;
#pragma unroll
            for (int k = 0; k < 4; ++k) {
                if (j & 1) { b0[k] += v * (float)g[j][k]; b1[k] += v * (float)g[j][k + 4]; }
                else       { a0[k] += v * (float)g[j][k]; a1[k] += v * (float)g[j][k + 4]; }
            }
        }
    }
#pragma unroll
    for (int k = 0; k < 4; ++k) { a0[k] += b0[k]; a1[k] += b1[k]; }
    float* op = out + (size_t)r * OUT_F + sub * 8;
    ((f32x4*)op)[0] = a0;
    ((f32x4*)op)[1] = a1;
}

extern "C" void kernel_launch(void* const* d_in, const int* in_sizes, int n_in,
                              void* d_out, int out_size, void* d_ws, size_t ws_size,
                              hipStream_t stream) {
    const float* x         = (const float*)d_in[0];
    const int*   edge_rows = (const int*)d_in[1];
    const int*   edge_cols = (const int*)d_in[2];
    const float* adj_vals  = (const float*)d_in[3];
    const float* weight    = (const float*)d_in[4];
    const float* bias      = (const float*)d_in[5];
    float* out = (float*)d_out;
    int nE = in_sizes[1];

    // ---- workspace layout, every section 64B-aligned (round-4 lesson:
    // unaligned `sorted` (long long*, was 4-mod-8) is the prime suspect for
    // the container fault) ----
    #define ALIGN64(p) (char*)(((size_t)(p) + 63) & ~(size_t)63)
    char* w = (char*)d_ws;
    __bf16* h  = (__bf16*)w;  w = ALIGN64(w + (size_t)N_NODES * OUT_F * sizeof(__bf16));
    __bf16* Wt = (__bf16*)w;  w = ALIGN64(w + (size_t)IN_F * OUT_F * sizeof(__bf16));
    int* deg    = (int*)w;    w += (size_t)NROWS * 4;          // | contiguous: zeroed
    int* bcnt   = (int*)w;    w += (size_t)NBUCKET * 4;        // | by one memset
    int* ov_cnt = (int*)w;    w = ALIGN64(w + 16);
    int* ov_idx = (int*)w;    w = ALIGN64(w + (size_t)MAX_OV * 4);
    int* row_start = (int*)w; w = ALIGN64(w + (size_t)(NROWS + 1) * 4);
    int* partial   = (int*)w; w = ALIGN64(w + (size_t)NBLK * 4);
    int* blockoff  = (int*)w; w = ALIGN64(w + (size_t)NBLK * 4);
    long long* sorted = (long long*)w;                                         // 25.6 MB

    // binned intermediate aliases d_out: 391*16384*8B = 51.2 MB < 102.4 MB,
    // fully dead before spmm overwrites out (stream-ordered).
    unsigned long long* inter = (unsigned long long*)d_out;

    hipMemsetAsync(deg, 0, (size_t)((char*)ov_cnt - (char*)deg) + 16, stream);
    prep_w_kernel<<<OUT_F, IN_F, 0, stream>>>(weight, Wt);

    int binBlocks = (nE + E_PER_BLK - 1) / E_PER_BLK;
    gemm_bin_kernel<<<GEMM_BLOCKS + binBlocks, 256, 0, stream>>>(
        x, Wt, bias, h, edge_rows, edge_cols, adj_vals,
        deg, bcnt, ov_cnt, ov_idx, inter, nE);

    partial_kernel<<<NBLK, 256, 0, stream>>>(deg, partial);
    scan_partial_kernel<<<1, 512, 0, stream>>>(partial, blockoff, row_start, nE);
    scan_rows_kernel<<<NBLK, 256, 0, stream>>>(deg, blockoff, row_start);

    bucket_sort_kernel<<<NBUCKET, 256, 0, stream>>>(row_start, inter, bcnt,
                                                    ov_cnt, ov_idx,
                                                    edge_rows, edge_cols, adj_vals,
                                                    sorted);

    spmm_csr_kernel<<<NROWS / 8, 256, 0, stream>>>(row_start, sorted, h, out);
}

// Round 6
// 608.475 us; speedup vs baseline: 1.3895x; 1.1131x over previous
//
#include <hip/hip_runtime.h>

#define N_NODES 100000
#define IN_F 256
#define OUT_F 256
#define NROWS N_NODES
#define MSTRIPS (N_NODES / 32)       // 3125 strips of 32 rows

// GEMM: 2 waves per strip (32 rows x 128 cols each), 4 waves/block
#define GWAVES (MSTRIPS * 2)              // 6250
#define GEMM_BLOCKS ((GWAVES + 3) / 4)    // 1563

// ---- bucketed counting sort params ----
#define RPB 256                       // rows per bucket (shift 8)
#define NBUCKET ((NROWS + RPB - 1) / RPB)   // 391
#define CAP 16384                     // bucket capacity (entries incl. padding)
#define CAPSH 14
#define E_PER_BLK 16384               // edges per bin block (64/thread)
#define SENT 0x2000000ULL             // lrow=256 (invalid) -> padding sentinel

typedef float f32x4 __attribute__((ext_vector_type(4)));
typedef __bf16 bf16x8 __attribute__((ext_vector_type(8)));

// ---------- W transpose + bf16 convert: Wt[n][k] ----------
__global__ __launch_bounds__(256) void prep_w_kernel(const float* __restrict__ W,
                                                     __bf16* __restrict__ Wt) {
    int n = blockIdx.x;
    int k = threadIdx.x;
    Wt[n * IN_F + k] = (__bf16)W[k * OUT_F + n];
}

// ---------- fused launch: GEMM blocks | bin blocks ----------
// GEMM: h = x @ W + bias, one wave per 32x128 sub-strip (unchanged).
// BIN: per 16384-edge block: (1) LDS bucket histogram, (2) reserve a
// LINE-ALIGNED chunk per bucket: rc = ceil(c/8)*8 entries via bres atomic
// (bucket base 128KB-aligned, so every chunk starts 64B-aligned and spans
// whole 64B lines -> full-line writebacks; round-5's 84B unaligned chunks
// caused 222MB of partial-line HBM writes @0.85 TB/s = the 268us).
// True counts accumulate in bcnt. (3) scatter packed entries
// (val<<32 | lrow<<17 | col), (4) fill pad slots with SENT.
// NO per-row deg atomics: bucket_sort derives per-row counts itself.
__global__ __launch_bounds__(256, 2) void gemm_bin_kernel(const float* __restrict__ x,
                                                          const __bf16* __restrict__ Wt,
                                                          const float* __restrict__ bias,
                                                          __bf16* __restrict__ h,
                                                          const int* __restrict__ rows,
                                                          const int* __restrict__ cols,
                                                          const float* __restrict__ vals,
                                                          int* __restrict__ bcnt,
                                                          int* __restrict__ bres,
                                                          unsigned long long* __restrict__ inter,
                                                          int nE) {
    __shared__ int cnt[NBUCKET];
    __shared__ int off[NBUCKET];
    __shared__ int off0[NBUCKET];

    if (blockIdx.x >= GEMM_BLOCKS) {
        // ================= BIN =================
        int bblk = blockIdx.x - GEMM_BLOCKS;
        int t = threadIdx.x;
        for (int i = t; i < NBUCKET; i += 256) cnt[i] = 0;
        __syncthreads();
        int base = bblk * E_PER_BLK;
        // phase 1: bucket histogram
#pragma unroll 4
        for (int j = 0; j < 16; ++j) {
            int e = base + (j * 256 + t) * 4;
            if (e + 3 < nE) {
                int4 rr = *(const int4*)(rows + e);
                atomicAdd(&cnt[rr.x >> 8], 1);
                atomicAdd(&cnt[rr.y >> 8], 1);
                atomicAdd(&cnt[rr.z >> 8], 1);
                atomicAdd(&cnt[rr.w >> 8], 1);
            } else {
                for (int k = 0; k < 4; ++k)
                    if (e + k < nE) atomicAdd(&cnt[rows[e + k] >> 8], 1);
            }
        }
        __syncthreads();
        // phase 2: reserve line-aligned chunks
        for (int i = t; i < NBUCKET; i += 256) {
            int c = cnt[i];
            if (c) {
                int rc = (c + 7) & ~7;
                int o = atomicAdd(&bres[i], rc);
                atomicAdd(&bcnt[i], c);
                int gb = (i << CAPSH) + o;
                off0[i] = gb;
                off[i] = gb;
            }
        }
        __syncthreads();
        // phase 3: scatter payload
#pragma unroll 2
        for (int j = 0; j < 16; ++j) {
            int e = base + (j * 256 + t) * 4;
            if (e + 3 < nE) {
                int4 rr = *(const int4*)(rows + e);
                int4 cc = *(const int4*)(cols + e);
                float4 vv = *(const float4*)(vals + e);
                int r4[4] = {rr.x, rr.y, rr.z, rr.w};
                int c4[4] = {cc.x, cc.y, cc.z, cc.w};
                float v4[4] = {vv.x, vv.y, vv.z, vv.w};
#pragma unroll
                for (int k = 0; k < 4; ++k) {
                    int r = r4[k];
                    int b = r >> 8;
                    int p = atomicAdd(&off[b], 1);
                    unsigned long long pk =
                        ((unsigned long long)__float_as_uint(v4[k]) << 32) |
                        ((unsigned)(r & (RPB - 1)) << 17) | (unsigned)c4[k];
                    if (p < ((b + 1) << CAPSH)) inter[p] = pk;
                }
            } else {
                for (int k = 0; k < 4; ++k) {
                    int ee = e + k;
                    if (ee < nE) {
                        int r = rows[ee];
                        int b = r >> 8;
                        int p = atomicAdd(&off[b], 1);
                        unsigned long long pk =
                            ((unsigned long long)__float_as_uint(vals[ee]) << 32) |
                            ((unsigned)(r & (RPB - 1)) << 17) | (unsigned)cols[ee];
                        if (p < ((b + 1) << CAPSH)) inter[p] = pk;
                    }
                }
            }
        }
        __syncthreads();
        // phase 4: sentinel padding (stays within the just-written lines)
        for (int i = t; i < NBUCKET; i += 256) {
            int c = cnt[i];
            if (c & 7) {
                int gb = off0[i];
                int lim = (i + 1) << CAPSH;
                int rc = (c + 7) & ~7;
                for (int s = c; s < rc; ++s)
                    if (gb + s < lim) inter[gb + s] = SENT;
            }
        }
        return;
    }

    // ================= GEMM =================
    int wave = (blockIdx.x << 2) | (threadIdx.x >> 6);
    if (wave >= GWAVES) return;
    int strip = wave >> 1;          // 32-row strip
    int nh = wave & 1;              // which 128-col half
    int lane = threadIdx.x & 63;
    int r16 = lane & 15;
    int quad = lane >> 4;

    const float*  xp0 = x + (size_t)(strip * 32 + r16) * IN_F + quad * 8;
    const float*  xp1 = xp0 + (size_t)16 * IN_F;
    const __bf16* wp  = Wt + (size_t)(nh * 128 + r16) * IN_F + quad * 8;

    f32x4 acc[2][8];
#pragma unroll
    for (int m = 0; m < 2; ++m)
#pragma unroll
        for (int i = 0; i < 8; ++i) acc[m][i] = (f32x4){0.f, 0.f, 0.f, 0.f};

#pragma unroll
    for (int k0 = 0; k0 < IN_F; k0 += 32) {
        f32x4 x00 = *(const f32x4*)(xp0 + k0);
        f32x4 x01 = *(const f32x4*)(xp0 + k0 + 4);
        f32x4 x10 = *(const f32x4*)(xp1 + k0);
        f32x4 x11 = *(const f32x4*)(xp1 + k0 + 4);
        bf16x8 a0, a1;
#pragma unroll
        for (int j = 0; j < 4; ++j) {
            a0[j] = (__bf16)x00[j]; a0[j + 4] = (__bf16)x01[j];
            a1[j] = (__bf16)x10[j]; a1[j + 4] = (__bf16)x11[j];
        }
#pragma unroll
        for (int nt = 0; nt < 8; ++nt) {
            bf16x8 b = *(const bf16x8*)(wp + (size_t)nt * 16 * IN_F + k0);
            acc[0][nt] = __builtin_amdgcn_mfma_f32_16x16x32_bf16(a0, b, acc[0][nt], 0, 0, 0);
            acc[1][nt] = __builtin_amdgcn_mfma_f32_16x16x32_bf16(a1, b, acc[1][nt], 0, 0, 0);
        }
    }

#pragma unroll
    for (int m = 0; m < 2; ++m)
#pragma unroll
        for (int nt = 0; nt < 8; ++nt) {
            int col = nh * 128 + nt * 16 + r16;
            float bv = bias[col];
            __bf16* hp = h + (size_t)(strip * 32 + m * 16 + quad * 4) * OUT_F + col;
#pragma unroll
            for (int r = 0; r < 4; ++r)
                hp[(size_t)r * OUT_F] = (__bf16)(acc[m][nt][r] + bv);
        }
}

// ---------- exclusive scan over 391 true bucket totals ----------
__global__ __launch_bounds__(512) void scan_buckets_kernel(const int* __restrict__ bcnt,
                                                           int* __restrict__ bucket_start,
                                                           int* __restrict__ row_start, int nE) {
    __shared__ int s[512];
    int t = threadIdx.x;
    int v = (t < NBUCKET) ? bcnt[t] : 0;
    s[t] = v;
    __syncthreads();
    for (int d = 1; d < 512; d <<= 1) {
        int u = (t >= d) ? s[t - d] : 0;
        __syncthreads();
        s[t] += u;
        __syncthreads();
    }
    if (t < NBUCKET) bucket_start[t] = s[t] - v;
    if (t == 0) row_start[NROWS] = nE;
}

// ---------- per-bucket: row histogram -> scan -> row_start -> scatter ----------
// One block per 256-row bucket. Phase A streams the bucket's inter segment
// (bres[b] entries incl. sentinels) building per-row counts in LDS; phase B
// scans them and writes row_start for these rows; phase C re-streams and
// scatters into final CSR order (destination window ~64-90KB: L2-local,
// full-line writebacks). Replaces the deg histogram + 3 scan kernels.
__global__ __launch_bounds__(256) void bucket_sort_kernel(const int* __restrict__ bres,
                                                          const int* __restrict__ bucket_start,
                                                          const unsigned long long* __restrict__ inter,
                                                          long long* __restrict__ sorted,
                                                          int* __restrict__ row_start) {
    __shared__ int hist[RPB];
    __shared__ int sc[RPB];
    __shared__ int cur[RPB];
    int t = threadIdx.x;
    int b = blockIdx.x;
    int r0 = b << 8;
    hist[t] = 0;
    __syncthreads();
    int n = bres[b]; if (n > CAP) n = CAP;
    const unsigned long long* src = inter + ((size_t)b << CAPSH);

    // phase A: per-row histogram (skip sentinels)
    int e0 = 0;
    for (; e0 + 1024 <= n; e0 += 1024) {
        unsigned m[4];
#pragma unroll
        for (int j = 0; j < 4; ++j) m[j] = (unsigned)src[e0 + j * 256 + t];
#pragma unroll
        for (int j = 0; j < 4; ++j) {
            int lr = (m[j] >> 17) & 0x1FF;
            if (lr < RPB) atomicAdd(&hist[lr], 1);
        }
    }
    for (int e = e0 + t; e < n; e += 256) {
        unsigned m = (unsigned)src[e];
        int lr = (m >> 17) & 0x1FF;
        if (lr < RPB) atomicAdd(&hist[lr], 1);
    }
    __syncthreads();

    // phase B: exclusive scan + row_start + cursors
    int v = hist[t];
    sc[t] = v;
    __syncthreads();
    for (int d = 1; d < RPB; d <<= 1) {
        int u = (t >= d) ? sc[t - d] : 0;
        __syncthreads();
        sc[t] += u;
        __syncthreads();
    }
    int bs = bucket_start[b];
    int excl = bs + sc[t] - v;
    int gr = r0 + t;
    if (gr < NROWS) row_start[gr] = excl;
    cur[t] = excl;
    __syncthreads();

    // phase C: scatter into final CSR order
    e0 = 0;
    for (; e0 + 1024 <= n; e0 += 1024) {
        unsigned long long pk[4];
#pragma unroll
        for (int j = 0; j < 4; ++j) pk[j] = src[e0 + j * 256 + t];
#pragma unroll
        for (int j = 0; j < 4; ++j) {
            unsigned meta = (unsigned)pk[j];
            int lr = (meta >> 17) & 0x1FF;
            if (lr < RPB) {
                int pos = atomicAdd(&cur[lr], 1);
                sorted[pos] = (long long)((pk[j] & 0xFFFFFFFF00000000ull) | (meta & 0x1FFFFu));
            }
        }
    }
    for (int e = e0 + t; e < n; e += 256) {
        unsigned long long pk = src[e];
        unsigned meta = (unsigned)pk;
        int lr = (meta >> 17) & 0x1FF;
        if (lr < RPB) {
            int pos = atomicAdd(&cur[lr], 1);
            sorted[pos] = (long long)((pk & 0xFFFFFFFF00000000ull) | (meta & 0x1FFFFu));
        }
    }
}

// ---------- SpMM: 2 rows/wave (32 lanes/row) ---------- (unchanged control)
__global__ __launch_bounds__(256, 4) void spmm_csr_kernel(const int* __restrict__ row_start,
                                                          const long long* __restrict__ sorted,
                                                          const __bf16* __restrict__ h,
                                                          float* __restrict__ out) {
    int half = threadIdx.x >> 5;           // 0..7 half-waves per block
    int sub  = threadIdx.x & 31;
    int r = blockIdx.x * 8 + half;
    int e0 = row_start[r];
    int e1 = row_start[r + 1];

    f32x4 a0 = {0.f,0.f,0.f,0.f}, a1 = {0.f,0.f,0.f,0.f};   // even edges
    f32x4 b0 = {0.f,0.f,0.f,0.f}, b1 = {0.f,0.f,0.f,0.f};   // odd edges

    int e = e0;
    if (e + 8 <= e1) {
        long long p[8];
#pragma unroll
        for (int j = 0; j < 8; ++j) p[j] = __builtin_nontemporal_load(sorted + e + j);
        e += 8;
        for (; e + 8 <= e1; e += 8) {
            bf16x8 g[8];
#pragma unroll
            for (int j = 0; j < 8; ++j)
                g[j] = ((const bf16x8*)(h + (size_t)(int)p[j] * OUT_F))[sub];
            long long q[8];
#pragma unroll
            for (int j = 0; j < 8; ++j) q[j] = __builtin_nontemporal_load(sorted + e + j);
#pragma unroll
            for (int j = 0; j < 8; ++j) {
                float v = __int_as_float((int)(p[j] >> 32));
#pragma unroll
                for (int k = 0; k < 4; ++k) {
                    if (j & 1) { b0[k] += v * (float)g[j][k]; b1[k] += v * (float)g[j][k + 4]; }
                    else       { a0[k] += v * (float)g[j][k]; a1[k] += v * (float)g[j][k + 4]; }
                }
            }
#pragma unroll
            for (int j = 0; j < 8; ++j) p[j] = q[j];
        }
        {
            bf16x8 g[8];
#pragma unroll
            for (int j = 0; j < 8; ++j)
                g[j] = ((const bf16x8*)(h + (size_t)(int)p[j] * OUT_F))[sub];
#pragma unroll
            for (int j = 0; j < 8; ++j) {
                float v = __int_as_float((int)(p[j] >> 32));
#pragma unroll
                for (int k = 0; k < 4; ++k) {
                    if (j & 1) { b0[k] += v * (float)g[j][k]; b1[k] += v * (float)g[j][k + 4]; }
                    else       { a0[k] += v * (float)g[j][k]; a1[k] += v * (float)g[j][k + 4]; }
                }
            }
        }
    }
    if (e < e1) {
        int rem = e1 - e;                   // 1..7
        long long t[8];
#pragma unroll
        for (int j = 0; j < 8; ++j) {
            int idx = e + j;
            if (idx > e1 - 1) idx = e1 - 1;
            t[j] = __builtin_nontemporal_load(sorted + idx);
        }
        bf16x8 g[8];
#pragma unroll
        for (int j = 0; j < 8; ++j)
            g[j] = ((const bf16x8*)(h + (size_t)(int)t[j] * OUT_F))[sub];
#pragma unroll
        for (int j = 0; j < 8; ++j) {
            float v = (j < rem) ? __int_as_float((int)(t[j] >> 32)) : 0.f;
#pragma unroll
            for (int k = 0; k < 4; ++k) {
                if (j & 1) { b0[k] += v * (float)g[j][k]; b1[k] += v * (float)g[j][k + 4]; }
                else       { a0[k] += v * (float)g[j][k]; a1[k] += v * (float)g[j][k + 4]; }
            }
        }
    }
#pragma unroll
    for (int k = 0; k < 4; ++k) { a0[k] += b0[k]; a1[k] += b1[k]; }
    float* op = out + (size_t)r * OUT_F + sub * 8;
    ((f32x4*)op)[0] = a0;
    ((f32x4*)op)[1] = a1;
}

extern "C" void kernel_launch(void* const* d_in, const int* in_sizes, int n_in,
                              void* d_out, int out_size, void* d_ws, size_t ws_size,
                              hipStream_t stream) {
    const float* x         = (const float*)d_in[0];
    const int*   edge_rows = (const int*)d_in[1];
    const int*   edge_cols = (const int*)d_in[2];
    const float* adj_vals  = (const float*)d_in[3];
    const float* weight    = (const float*)d_in[4];
    const float* bias      = (const float*)d_in[5];
    float* out = (float*)d_out;
    int nE = in_sizes[1];

    // ---- workspace layout, every section 64B-aligned ----
    #define ALIGN64(p) (char*)(((size_t)(p) + 63) & ~(size_t)63)
    char* w = (char*)d_ws;
    __bf16* h  = (__bf16*)w;  w = ALIGN64(w + (size_t)N_NODES * OUT_F * sizeof(__bf16));
    __bf16* Wt = (__bf16*)w;  w = ALIGN64(w + (size_t)IN_F * OUT_F * sizeof(__bf16));
    int* bcnt = (int*)w;      w += (size_t)NBUCKET * 4;   // | contiguous: zeroed
    int* bres = (int*)w;      w = ALIGN64(w + (size_t)NBUCKET * 4);  // | by one memset
    int* bucket_start = (int*)w; w = ALIGN64(w + (size_t)NBUCKET * 4);
    int* row_start = (int*)w; w = ALIGN64(w + (size_t)(NROWS + 1) * 4);
    long long* sorted = (long long*)w;                                         // 25.6 MB

    // binned intermediate aliases d_out: 391*16384*8B = 51.2 MB < 102.4 MB,
    // fully dead before spmm overwrites out (stream-ordered).
    unsigned long long* inter = (unsigned long long*)d_out;

    hipMemsetAsync(bcnt, 0, (size_t)NBUCKET * 2 * 4, stream);
    prep_w_kernel<<<OUT_F, IN_F, 0, stream>>>(weight, Wt);

    int binBlocks = (nE + E_PER_BLK - 1) / E_PER_BLK;
    gemm_bin_kernel<<<GEMM_BLOCKS + binBlocks, 256, 0, stream>>>(
        x, Wt, bias, h, edge_rows, edge_cols, adj_vals,
        bcnt, bres, inter, nE);

    scan_buckets_kernel<<<1, 512, 0, stream>>>(bcnt, bucket_start, row_start, nE);

    bucket_sort_kernel<<<NBUCKET, 256, 0, stream>>>(bres, bucket_start, inter,
                                                    sorted, row_start);

    spmm_csr_kernel<<<NROWS / 8, 256, 0, stream>>>(row_start, sorted, h, out);
}